// Round 1
// baseline (58.596 us; speedup 1.0000x reference)
//
#include <hip/hip_runtime.h>

// Problem constants (match reference setup_inputs).
constexpr int B       = 4096;
constexpr int W_ENC   = 8192;
constexpr int MAX_LEN = 4096;
constexpr int VPR     = W_ENC / 4;   // float4 vectors per output row = 2048

// y[i][j] = concat(prev[i], ragged[i])[j + L_i], j in [0, W_ENC)
// lens_out[i] = (float)L_i   (harness reads the whole d_out as float32)
__global__ __launch_bounds__(256) void frames_gather_kernel(
        const float* __restrict__ prev,
        const float* __restrict__ ragged,
        const int*   __restrict__ row_lengths,
        float*       __restrict__ out) {
    const long total = (long)B * VPR;
    float* __restrict__ lens_out = out + (size_t)B * W_ENC;

    for (long t = (long)blockIdx.x * blockDim.x + threadIdx.x; t < total;
         t += (long)gridDim.x * blockDim.x) {
        const int i  = (int)(t >> 11);          // t / VPR
        const int jv = (int)(t & (VPR - 1));    // t % VPR
        const int L  = row_lengths[i];          // wave-uniform -> scalar cached

        if (jv == 0) lens_out[i] = (float)L;

        const int base = jv * 4 + L;            // start col in concat space, <= 12286
        const float* __restrict__ prow = prev   + (size_t)i * W_ENC;
        const float* __restrict__ rrow = ragged + (size_t)i * MAX_LEN;

        float4 o;
        if (base + 3 < W_ENC) {
            // Entirely from prev (wave-uniform fast path; dword-misaligned but coalesced).
            o.x = prow[base + 0];
            o.y = prow[base + 1];
            o.z = prow[base + 2];
            o.w = prow[base + 3];
        } else if (base >= W_ENC) {
            // Entirely from ragged.
            const float* __restrict__ r = rrow + (base - W_ENC);
            o.x = r[0];
            o.y = r[1];
            o.z = r[2];
            o.w = r[3];
        } else {
            // Boundary vector (at most one per row): per-element select.
            float v[4];
            #pragma unroll
            for (int k = 0; k < 4; ++k) {
                const int c = base + k;
                v[k] = (c < W_ENC) ? prow[c] : rrow[c - W_ENC];
            }
            o.x = v[0]; o.y = v[1]; o.z = v[2]; o.w = v[3];
        }

        // Aligned 16B store of the output row vector.
        reinterpret_cast<float4*>(out + (size_t)i * W_ENC)[jv] = o;
    }
}

extern "C" void kernel_launch(void* const* d_in, const int* in_sizes, int n_in,
                              void* d_out, int out_size, void* d_ws, size_t ws_size,
                              hipStream_t stream) {
    const float* prev        = (const float*)d_in[0];
    const float* ragged_vals = (const float*)d_in[1];
    const int*   row_lengths = (const int*)d_in[2];
    float*       out         = (float*)d_out;

    // Memory-bound: ~2048 blocks + grid-stride (Guideline 11).
    const int block = 256;
    const int grid  = 2048;
    frames_gather_kernel<<<grid, block, 0, stream>>>(prev, ragged_vals, row_lengths, out);
}

// Round 2
// 55.877 us; speedup vs baseline: 1.0487x; 1.0487x over previous
//
#include <hip/hip_runtime.h>

// Problem constants (match reference setup_inputs).
constexpr int B       = 4096;
constexpr int W_ENC   = 8192;
constexpr int MAX_LEN = 4096;
constexpr int VPR     = W_ENC / 4;     // float4 vectors per output row = 2048
constexpr int CVPR    = (W_ENC + MAX_LEN) / 4;  // concat row in vectors = 3072

// Aligned float4 from the virtual concat row [prev(2048 vecs) | ragged(1024 vecs)].
// The concat boundary is vector-aligned, so each aligned vector is entirely in
// one array. Pointer-select (cndmask on address) -> single load, no divergence.
__device__ __forceinline__ float4 cvec(const float4* __restrict__ pv,
                                       const float4* __restrict__ rv, int v) {
    const float4* p = (v < VPR) ? (pv + v) : (rv + (v - VPR));
    return *p;
}

// y[i][j] = concat(prev[i], ragged[i])[j + L_i], j in [0, W_ENC)
// lens_out[i] = (float)L_i
__global__ __launch_bounds__(256) void frames_gather_kernel(
        const float* __restrict__ prev,
        const float* __restrict__ ragged,
        const int*   __restrict__ row_lengths,
        float*       __restrict__ out) {
    float* __restrict__ lens_out = out + (size_t)B * W_ENC;

    // Exact grid: one output float4 per thread, no grid-stride serialization.
    const int t  = blockIdx.x * blockDim.x + threadIdx.x;   // < B*VPR = 8.4M
    const int i  = t >> 11;          // row (2048 vectors/row; wave-uniform)
    const int jv = t & (VPR - 1);    // output vector index within row
    const int L  = row_lengths[i];   // wave-uniform broadcast load (L1 hit)

    if (jv == 0) lens_out[i] = (float)L;

    const float4* __restrict__ pv =
        (const float4*)(prev   + (size_t)i * W_ENC);
    const float4* __restrict__ rv =
        (const float4*)(ragged + (size_t)i * MAX_LEN);

    const int q  = L >> 2;           // vector shift
    const int r  = L & 3;            // dword remainder (wave-uniform)
    const int vA = q + jv;           // first aligned source vector (< 3072)

    const float4 A = cvec(pv, rv, vA);
    float4 o;
    if (r == 0) {
        // Aligned fast path: single 16B load.
        o = A;
    } else {
        // Two aligned 16B loads + register rotate. vA+1 <= 3071, never OOB.
        const float4 Bv = cvec(pv, rv, vA + 1);
        switch (r) {   // wave-uniform branch, pure register shuffles
        case 1:  o = make_float4(A.y, A.z, A.w, Bv.x); break;
        case 2:  o = make_float4(A.z, A.w, Bv.x, Bv.y); break;
        default: o = make_float4(A.w, Bv.x, Bv.y, Bv.z); break;
        }
    }

    // Aligned 16B output store.
    reinterpret_cast<float4*>(out + (size_t)i * W_ENC)[jv] = o;
}

extern "C" void kernel_launch(void* const* d_in, const int* in_sizes, int n_in,
                              void* d_out, int out_size, void* d_ws, size_t ws_size,
                              hipStream_t stream) {
    const float* prev        = (const float*)d_in[0];
    const float* ragged_vals = (const float*)d_in[1];
    const int*   row_lengths = (const int*)d_in[2];
    float*       out         = (float*)d_out;

    const int block = 256;
    const int grid  = (B * VPR) / block;   // 32768 blocks, exact
    frames_gather_kernel<<<grid, block, 0, stream>>>(prev, ragged_vals, row_lengths, out);
}

// Round 4
// 44.922 us; speedup vs baseline: 1.3044x; 1.2439x over previous
//
#include <hip/hip_runtime.h>

// Problem constants (match reference setup_inputs).
constexpr int B       = 4096;
constexpr int W_ENC   = 8192;
constexpr int MAX_LEN = 4096;
constexpr int VPR     = W_ENC / 4;   // float4 vectors per output row = 2048
constexpr int BLOCK   = 256;
constexpr int VPT     = VPR / BLOCK; // vectors per thread = 8

// Native clang vector type: works with __builtin_nontemporal_store
// (HIP_vector_type float4 does not).
typedef float fx4 __attribute__((ext_vector_type(4)));

// Aligned fx4 from the virtual concat row [prev(2048 vecs) | ragged(1024 vecs)].
// Concat boundary is vector-aligned -> each aligned vector lives entirely in one
// array; pointer-select is a cndmask on the address, no divergence cost.
__device__ __forceinline__ fx4 cvec(const fx4* __restrict__ pv,
                                    const fx4* __restrict__ rv, int v) {
    const fx4* p = (v < VPR) ? (pv + v) : (rv + (v - VPR));
    return *p;
}

// One row, remainder R = L&3 known at compile time (switched once per block).
// Issue all loads first (MLP), then rotate+store. All indices compile-time ->
// everything stays in registers (no scratch).
template <int R>
__device__ __forceinline__ void do_row(const fx4* __restrict__ pv,
                                       const fx4* __restrict__ rv,
                                       fx4* __restrict__ ov,
                                       int q, int tid) {
    fx4 A[VPT];
    fx4 Bv[VPT];
    #pragma unroll
    for (int m = 0; m < VPT; ++m) {
        const int vA = q + tid + m * BLOCK;   // <= 1023+255+1792 = 3070
        A[m] = cvec(pv, rv, vA);
        if (R != 0) Bv[m] = cvec(pv, rv, vA + 1);   // <= 3071 < 3072, never OOB
    }
    #pragma unroll
    for (int m = 0; m < VPT; ++m) {
        fx4 o;
        if      (R == 0) o = A[m];
        else if (R == 1) o = fx4{A[m].y, A[m].z, A[m].w, Bv[m].x};
        else if (R == 2) o = fx4{A[m].z, A[m].w, Bv[m].x, Bv[m].y};
        else             o = fx4{A[m].w, Bv[m].x, Bv[m].y, Bv[m].z};
        // Non-temporal: output is write-once; keep inputs resident in L2/L3.
        __builtin_nontemporal_store(o, ov + tid + m * BLOCK);
    }
}

// y[i][j] = concat(prev[i], ragged[i])[j + L_i], j in [0, W_ENC)
// lens_out[i] = (float)L_i
__global__ __launch_bounds__(BLOCK) void frames_gather_kernel(
        const float* __restrict__ prev,
        const float* __restrict__ ragged,
        const int*   __restrict__ row_lengths,
        float*       __restrict__ out) {
    const int i = blockIdx.x;            // one block per row
    const int L = row_lengths[i];        // block-uniform -> scalar s_load

    if (threadIdx.x == 0) {
        out[(size_t)B * W_ENC + i] = (float)L;   // lens output
    }

    const fx4* __restrict__ pv = (const fx4*)(prev   + (size_t)i * W_ENC);
    const fx4* __restrict__ rv = (const fx4*)(ragged + (size_t)i * MAX_LEN);
    fx4* __restrict__ ov       = (fx4*)(out + (size_t)i * W_ENC);

    const int q   = L >> 2;   // vector shift
    const int tid = threadIdx.x;

    switch (L & 3) {          // wave-uniform, branched exactly once
    case 0:  do_row<0>(pv, rv, ov, q, tid); break;
    case 1:  do_row<1>(pv, rv, ov, q, tid); break;
    case 2:  do_row<2>(pv, rv, ov, q, tid); break;
    default: do_row<3>(pv, rv, ov, q, tid); break;
    }
}

extern "C" void kernel_launch(void* const* d_in, const int* in_sizes, int n_in,
                              void* d_out, int out_size, void* d_ws, size_t ws_size,
                              hipStream_t stream) {
    const float* prev        = (const float*)d_in[0];
    const float* ragged_vals = (const float*)d_in[1];
    const int*   row_lengths = (const int*)d_in[2];
    float*       out         = (float*)d_out;

    frames_gather_kernel<<<B, BLOCK, 0, stream>>>(prev, ragged_vals, row_lengths, out);
}